// Round 2
// 208.096 us; speedup vs baseline: 1.0130x; 1.0130x over previous
//
#include <hip/hip_runtime.h>
#include <hip/hip_bf16.h>
#include <math.h>

// ---------------------------------------------------------------------------
// FullAttentionEstimator — fully MFMA-based pipeline.
//   k_prep: weight sums + bf16 transposed weights (WT u/v with Wo folded in u;
//           WqT/WkT for projection B-operands).
//   k_proj: q=Q@Wq, k=K@Wk via MFMA (8 rows/block, 256 blocks), + stats + P/R.
//   k_main: S=(k⊙q_i)@W3 via MFMA; LN + gelu + Wo-dot epilogue.
// Lessons encoded (hard-won):
//  * (256,4) hard-spills w3f (R6: 237MB fetch); any +16 VGPR of per-thread
//    state at (256,3) soft-spills (R8 qn: 34MB, R11 ruR/rvR: 63MB WRITE).
//  * shfl-heavy epilogue reductions lose to LDS red2 (R7, R10 regressed).
//  * dbuf/1-barrier-per-iter lost to plain 2-barrier (R10: 124 vs R9: 110).
// R12: restructure k_main to 512 thr / 8 waves, 16 h-cols per wave: per-thread
//  state halves (w3f 64->32, acc 32->16, kreg 16->8) so __launch_bounds__(512,4)
//  = 2 blocks x 8 waves = 16 waves/CU without spills. (Bench infra-failed.)
// R13 (this round): R12 resubmit with alignment fixes. R12's ASTR=134 made the
//  MFMA A-read ds_read_b128 only 4B-aligned (268B row stride) — UB and a
//  plausible fault/hang cause. Now ASTR=152 shorts = 76 dw: 76 ≡ 0 mod 4
//  (all b128 LDS ops 16B-aligned, legal) and 76 ≡ 12 mod 32 (per 8-lane group,
//  cols hit 8 distinct 4-dword bank slots → conflict-free A-reads).
//  RSTR 130->132 (aligned, 2-way max). Tail red2 read interleaved (k*4+c4*16):
//  4-way -> 2-way (free).
// ---------------------------------------------------------------------------

#define EPSLN 1e-5f

// workspace layout (float offsets)
#define WS_QP   0            // 1024 x 128 projected q (fp32)
#define WS_KP   131072
#define WS_PU   262144       // Wo-scaled
#define WS_PV   393216
#define WS_RU   524288       // Wo-scaled
#define WS_RV   655360
#define WS_SQ   786432
#define WS_QQ   787456
#define WS_SK   788480
#define WS_KK   789504
#define WS_GUS  790528
#define WS_GVS  790656
#define WS_CU   790784
#define WS_CV   790912
#define WS_WTU  791040       // bf16 [128 h][384 c] = g⊙Wu^T, Wo-scaled
#define WS_WTV  815616       // bf16 [128 h][384 c] = g⊙Wv^T
#define WS_WQT  840192       // bf16 [128 h][1024 d] = Wq^T
#define WS_WKT  905728       // bf16 [128 h][1024 d] = Wk^T
// end 971264 floats = 3.89 MB

typedef __attribute__((ext_vector_type(8))) short short8;
typedef __attribute__((ext_vector_type(4))) float f32x4;

__device__ inline unsigned short f2bf(float x) {
    unsigned u = __builtin_bit_cast(unsigned, x);
    unsigned r = u + 0x7fffu + ((u >> 16) & 1u);
    return (unsigned short)(r >> 16);
}
__device__ inline float b2f_lo(unsigned v) { return __builtin_bit_cast(float, v << 16); }
__device__ inline float b2f_hi(unsigned v) { return __builtin_bit_cast(float, v & 0xffff0000u); }
__device__ inline unsigned pack_bf2(float a, float b) {   // v_cvt_pk_bf16_f32
    __hip_bfloat162 h = __float22bfloat162_rn(make_float2(a, b));
    unsigned r;
    __builtin_memcpy(&r, &h, 4);
    return r;
}
__device__ inline void store8(unsigned short* p, const unsigned short* v) {
    short8 s;
    #pragma unroll
    for (int e = 0; e < 8; ++e) s[e] = (short)v[e];
    *(short8*)p = s;
}
#define GELU_C1 2.3022035f
#define GELU_C2 0.1029431f
__device__ inline float fast_gelu(float v) {
    float ex = __builtin_amdgcn_exp2f(v * fmaf(v * v, GELU_C2, GELU_C1));
    float r  = __builtin_amdgcn_rcpf(ex + 1.f);
    return v - v * r;
}

// ---------------- kernel 1: weight prep (24 blocks x 256) -----------------
__global__ __launch_bounds__(256, 2)
void k_prep(const float* __restrict__ Wu, const float* __restrict__ bu,
            const float* __restrict__ Wv, const float* __restrict__ bv,
            const float* __restrict__ g, const float* __restrict__ bln,
            const float* __restrict__ Wo,
            const float* __restrict__ Wq, const float* __restrict__ Wk,
            float* __restrict__ ws) {
    int task = blockIdx.x, t = threadIdx.x;
    if (task < 2) {
        bool isV = task != 0;
        const float* W  = isV ? Wv : Wu;
        const float* bb = isV ? bv : bu;
        float* gout = ws + (isV ? WS_GVS : WS_GUS);
        float* cout = ws + (isV ? WS_CV : WS_CU);
        __shared__ float rg[2][128], rc[2][128];
        int tl = t & 127, g2 = t >> 7;
        float gu = 0.f, cu = 0.f;
        for (int c = g2 * 192; c < g2 * 192 + 192; ++c) {
            float wv_ = W[c * 128 + tl];
            gu += g[c] * wv_;
            cu += bln[c] * wv_;
        }
        rg[g2][tl] = gu; rc[g2][tl] = cu;
        __syncthreads();
        if (t < 128) gout[t] = rg[0][t] + rg[1][t];
        else { int h = t - 128; cout[h] = rc[0][h] + rc[1][h] + bb[h]; }
    } else if (task < 8) {
        int tt = task - 2;
        bool isV = tt >= 3;
        int seg = tt % 3;
        const float* W = isV ? Wv : Wu;
        unsigned short* wt = (unsigned short*)(ws + (isV ? WS_WTV : WS_WTU));
        __shared__ unsigned short tile[128 * 130];
        for (int it = 0; it < 64; ++it) {
            int idx = t + 256 * it;
            int c = idx >> 7, h = idx & 127;
            float s = g[seg * 128 + c] * (isV ? 1.f : Wo[h]);
            tile[c * 130 + h] = f2bf(s * W[(seg * 128 + c) * 128 + h]);
        }
        __syncthreads();
        int h = t >> 1, c0 = (t & 1) * 64;
        for (int cc = 0; cc < 64; cc += 8) {
            unsigned short v[8];
            #pragma unroll
            for (int e = 0; e < 8; ++e) v[e] = tile[(c0 + cc + e) * 130 + h];
            store8(&wt[h * 384 + seg * 128 + c0 + cc], v);
        }
    } else {
        int tt = task - 8;
        const float* W = (tt >> 3) ? Wk : Wq;
        unsigned short* wt = (unsigned short*)(ws + ((tt >> 3) ? WS_WKT : WS_WQT));
        int seg = tt & 7;
        __shared__ unsigned short tile[128 * 130];
        for (int it = 0; it < 64; ++it) {
            int idx = t + 256 * it;
            int c = idx >> 7, h = idx & 127;
            tile[c * 130 + h] = f2bf(W[(size_t)(seg * 128 + c) * 128 + h]);
        }
        __syncthreads();
        int h = t >> 1, c0 = (t & 1) * 64;
        for (int cc = 0; cc < 64; cc += 8) {
            unsigned short v[8];
            #pragma unroll
            for (int e = 0; e < 8; ++e) v[e] = tile[(c0 + cc + e) * 130 + h];
            store8(&wt[h * 1024 + seg * 128 + c0 + cc], v);
        }
    }
}

// ---------------- kernel 2: MFMA projection + stats + P/R -----------------
// 256 blocks x 256 thr; 8 rows/block (blocks 0..127: Q, 128..255: K).
// m-tile rows 8..15 are never staged/stored: MFMA rows are independent, so
// garbage in those A rows only produces garbage in C rows we never read.
#define XST 1028   // staged-row stride (shorts): 514 uints == 2 mod 32
#define QST 132    // qpL stride (shorts): 66 uints == 2 mod 32
__global__ __launch_bounds__(256, 2)
void k_proj(const float* __restrict__ Q, const float* __restrict__ K,
            float* __restrict__ ws) {
    int blk = blockIdx.x, t = threadIdx.x;
    bool isK = blk >= 128;
    int r0 = (blk & 127) * 8;
    const float* src = isK ? K : Q;
    const unsigned short* wtin = (const unsigned short*)(ws + (isK ? WS_WKT : WS_WQT));
    float* dst = ws + (isK ? WS_KP : WS_QP);
    int L = t & 63, w = t >> 6;
    int col = L & 15, quad = L >> 4;

    __shared__ unsigned short XLb[16 * XST];
    __shared__ unsigned short qpL[16 * QST];
    __shared__ float sp1[16][4], sp2[16][4];

    {   // stage 8 rows x 1024 d as bf16 (rows 8..15 left stale — unused)
        int srow = t >> 5;
        int c0 = (t & 31) * 4;
        const float* sp = src + (size_t)(r0 + srow) * 1024;
        #pragma unroll
        for (int g8 = 0; g8 < 8; ++g8) {
            float4 xv = *(const float4*)(sp + g8 * 128 + c0);
            unsigned* xp = (unsigned*)&XLb[srow * XST + g8 * 128 + c0];
            xp[0] = pack_bf2(xv.x, xv.y);
            xp[1] = pack_bf2(xv.z, xv.w);
        }
    }
    __syncthreads();

    f32x4 acc[2];
    acc[0] = (f32x4){0.f, 0.f, 0.f, 0.f};
    acc[1] = (f32x4){0.f, 0.f, 0.f, 0.f};
    #pragma unroll 4
    for (int ks = 0; ks < 32; ++ks) {
        short8 a = *(const short8*)&XLb[col * XST + ks * 32 + quad * 8];
        #pragma unroll
        for (int nt2 = 0; nt2 < 2; ++nt2) {
            int h = w * 32 + nt2 * 16 + col;
            short8 b = *(const short8*)&wtin[(size_t)h * 1024 + ks * 32 + quad * 8];
            acc[nt2] = __builtin_amdgcn_mfma_f32_16x16x32_bf16(a, b, acc[nt2], 0, 0, 0);
        }
    }

    #pragma unroll
    for (int r = 0; r < 4; ++r) {
        int row = quad * 4 + r;
        float s1 = acc[0][r] + acc[1][r];
        float s2 = acc[0][r] * acc[0][r] + acc[1][r] * acc[1][r];
        #pragma unroll
        for (int d = 1; d < 16; d <<= 1) { s1 += __shfl_xor(s1, d); s2 += __shfl_xor(s2, d); }
        if (col == 0) { sp1[row][w] = s1; sp2[row][w] = s2; }
        #pragma unroll
        for (int nt2 = 0; nt2 < 2; ++nt2) {
            int h = w * 32 + nt2 * 16 + col;
            qpL[row * QST + h] = f2bf(acc[nt2][r]);
            if (row < 8) dst[(size_t)(r0 + row) * 128 + h] = acc[nt2][r];
        }
    }
    __syncthreads();
    if (t < 8) {
        ws[(isK ? WS_SK : WS_SQ) + r0 + t] = (sp1[t][0] + sp1[t][1]) + (sp1[t][2] + sp1[t][3]);
        ws[(isK ? WS_KK : WS_QQ) + r0 + t] = (sp2[t][0] + sp2[t][1]) + (sp2[t][2] + sp2[t][3]);
    }

    int uv = w & 1, nhf = w >> 1;
    const unsigned short* wt = (const unsigned short*)(ws + (uv ? WS_WTV : WS_WTU));
    int cb0 = isK ? 128 : 0;
    f32x4 pacc[4];
    #pragma unroll
    for (int nt = 0; nt < 4; ++nt) pacc[nt] = (f32x4){0.f, 0.f, 0.f, 0.f};
    #pragma unroll
    for (int ks = 0; ks < 4; ++ks) {
        short8 a = *(const short8*)&qpL[col * QST + ks * 32 + quad * 8];
        #pragma unroll
        for (int nt = 0; nt < 4; ++nt) {
            int h = nhf * 64 + nt * 16 + col;
            short8 b = *(const short8*)&wt[h * 384 + cb0 + ks * 32 + quad * 8];
            pacc[nt] = __builtin_amdgcn_mfma_f32_16x16x32_bf16(a, b, pacc[nt], 0, 0, 0);
        }
    }
    float* PO = ws + (uv ? (isK ? WS_RV : WS_PV) : (isK ? WS_RU : WS_PU));
    #pragma unroll
    for (int nt = 0; nt < 4; ++nt)
        #pragma unroll
        for (int r = 0; r < 4; ++r) {
            int row = quad * 4 + r;
            if (row < 8)
                PO[(size_t)(r0 + row) * 128 + nhf * 64 + nt * 16 + col] = pacc[nt][r];
        }
}

// ---------------- kernel 3: MFMA main (R13: 512 thr / 8 waves) -------------
// grid 2048 = 2 b x 64 i-groups x 16 j-tiles; 512 thr / 8 waves; wave w owns
// h-cols [w*16, w*16+16) for BOTH u and v. Same 3-barrier/iter schedule as R9.
#define ASTR 152   // bf16 A stride: 76 dw ≡ 12 mod 32 → conflict-free, 16B-aligned
#define RSTR 132   // packed (ru',rv) stride (uints): ≡ 4 mod 32, 16B-aligned
#define REDS 132   // red2 row stride (floats), 128 entries/row
__global__ __launch_bounds__(512, 4)
void k_main(const float* __restrict__ ws, float* __restrict__ out,
            const float* __restrict__ Wo, const float* __restrict__ bo) {
    int blk = blockIdx.x;
    int jt = blk & 15, ig = (blk >> 4) & 63, b = blk >> 10;
    int t = threadIdx.x;
    int L = t & 63, w = t >> 6;          // 8 waves
    int col = L & 15, quad = L >> 4;
    int krow0 = b * 512 + jt * 32;
    int jj = t >> 4, cb = (t & 15) * 8;  // staging: row jj, c-range [cb, cb+8)
    int h = w * 16 + col;                // this wave's h-column

    __shared__ unsigned short Alds[32 * ASTR];
    __shared__ unsigned ruvL[32 * RSTR];
    __shared__ float red2[32 * REDS];
    __shared__ float skL[32], kkL[32];
    __shared__ float muL[32], rsL[32];

    // ---- block-invariant staging ----
    float kreg[8];
    {
        const float* kp = ws + WS_KP + (size_t)(krow0 + jj) * 128 + cb;
        #pragma unroll
        for (int e = 0; e < 8; ++e) kreg[e] = kp[e];
        const float* rup = ws + WS_RU + (size_t)(krow0 + jj) * 128 + cb;
        const float* rvp = ws + WS_RV + (size_t)(krow0 + jj) * 128 + cb;
        unsigned pk[8];
        #pragma unroll
        for (int e = 0; e < 8; ++e) pk[e] = pack_bf2(rup[e], rvp[e]);
        unsigned* rr = &ruvL[jj * RSTR + cb];
        *(uint4*)&rr[0] = *(uint4*)&pk[0];
        *(uint4*)&rr[4] = *(uint4*)&pk[4];
    }
    if (t < 32) { skL[t] = ws[WS_SK + krow0 + t]; kkL[t] = ws[WS_KK + krow0 + t]; }

    // W3 fragments (c 256..384 of WT) for this wave's 16 h-cols: 32 VGPRs
    short8 w3f[2][4];
    {
        const unsigned short* wtu = (const unsigned short*)(ws + WS_WTU);
        const unsigned short* wtv = (const unsigned short*)(ws + WS_WTV);
        #pragma unroll
        for (int ks = 0; ks < 4; ++ks) {
            w3f[0][ks] = *(const short8*)&wtu[h * 384 + 256 + ks * 32 + quad * 8];
            w3f[1][ks] = *(const short8*)&wtv[h * 384 + 256 + ks * 32 + quad * 8];
        }
    }
    float wo  = Wo[h];
    float gusv = ws[WS_GUS + h] * wo;
    float cuv  = ws[WS_CU + h] * wo;
    float gvsv = ws[WS_GVS + h];
    float cvv  = ws[WS_CV + h];
    float bo0 = bo[0];
    int bi0 = b * 512 + ig * 8;
    __syncthreads();

    #pragma unroll 1
    for (int ii = 0; ii < 8; ++ii) {
        int bi = bi0 + ii;
        // ---- stage A = k ⊙ q_i (bf16) + fused stats via intra-16-lane shfl ----
        {
            const float4* qp4 = (const float4*)(ws + WS_QP + (size_t)bi * 128 + cb);
            float d1 = 0.f, d2 = 0.f;
            unsigned pk[4];
            #pragma unroll
            for (int e4 = 0; e4 < 2; ++e4) {
                float4 qv = qp4[e4];
                float x0 = kreg[e4 * 4]     * qv.x, x1 = kreg[e4 * 4 + 1] * qv.y;
                float x2 = kreg[e4 * 4 + 2] * qv.z, x3 = kreg[e4 * 4 + 3] * qv.w;
                d1 += (x0 + x1) + (x2 + x3);
                d2 += (x0 * x0 + x1 * x1) + (x2 * x2 + x3 * x3);
                pk[e4 * 2]     = pack_bf2(x0, x1);
                pk[e4 * 2 + 1] = pack_bf2(x2, x3);
            }
            unsigned* arow = (unsigned*)Alds + jj * (ASTR / 2) + cb / 2;
            *(uint4*)&arow[0] = *(uint4*)&pk[0];
            d1 += __shfl_xor(d1, 1); d2 += __shfl_xor(d2, 1);
            d1 += __shfl_xor(d1, 2); d2 += __shfl_xor(d2, 2);
            d1 += __shfl_xor(d1, 4); d2 += __shfl_xor(d2, 4);
            d1 += __shfl_xor(d1, 8); d2 += __shfl_xor(d2, 8);
            if ((t & 15) == 0) {
                float mu = (ws[WS_SQ + bi] + skL[jj] + d1) * (1.0f / 384.0f);
                float e2 = (ws[WS_QQ + bi] + kkL[jj] + d2) * (1.0f / 384.0f);
                muL[jj] = mu;
                rsL[jj] = rsqrtf(e2 - mu * mu + EPSLN);
            }
        }
        __syncthreads();                                     // B1: Alds + muL/rsL ready
        // ---- K-loop: S = A @ W3 via MFMA (16 MFMA / wave / iter) ----
        f32x4 acc[2][2];
        #pragma unroll
        for (int mt = 0; mt < 2; ++mt)
            #pragma unroll
            for (int uv = 0; uv < 2; ++uv) acc[mt][uv] = (f32x4){0.f, 0.f, 0.f, 0.f};
        #pragma unroll
        for (int ks = 0; ks < 4; ++ks) {
            short8 a0 = *(const short8*)&Alds[col * ASTR + ks * 32 + quad * 8];
            short8 a1 = *(const short8*)&Alds[(col + 16) * ASTR + ks * 32 + quad * 8];
            acc[0][0] = __builtin_amdgcn_mfma_f32_16x16x32_bf16(a0, w3f[0][ks], acc[0][0], 0, 0, 0);
            acc[0][1] = __builtin_amdgcn_mfma_f32_16x16x32_bf16(a0, w3f[1][ks], acc[0][1], 0, 0, 0);
            acc[1][0] = __builtin_amdgcn_mfma_f32_16x16x32_bf16(a1, w3f[0][ks], acc[1][0], 0, 0, 0);
            acc[1][1] = __builtin_amdgcn_mfma_f32_16x16x32_bf16(a1, w3f[1][ks], acc[1][1], 0, 0, 0);
        }
        float puv = ws[WS_PU + (size_t)bi * 128 + h];         // Wo-scaled
        float pvv = ws[WS_PV + (size_t)bi * 128 + h];
        __syncthreads();                                     // B2: muL/rsL consumed-safe
        // ---- epilogue: u', v, fast-gelu -> red2 ----
        #pragma unroll
        for (int mt = 0; mt < 2; ++mt) {
            #pragma unroll
            for (int r = 0; r < 4; ++r) {
                int jl = mt * 16 + quad * 4 + r;
                float rs = rsL[jl];
                float rsmu = rs * muL[jl];
                unsigned pr = ruvL[jl * RSTR + h];
                float su  = acc[mt][0][r] + puv + b2f_lo(pr);
                float u   = fmaf(rs, su, fmaf(-rsmu, gusv, cuv));
                float sv_ = acc[mt][1][r] + pvv + b2f_hi(pr);
                float v   = fmaf(rs, sv_, fmaf(-rsmu, gvsv, cvv));
                red2[jl * REDS + w * 16 + col] = u * fast_gelu(v);
            }
        }
        __syncthreads();                                     // B3: red2 ready / Alds free
        if (t < 128) {
            // interleaved float4 chunks (k*4 + c4*16 dwords): 2-way banks (free)
            const float4* rr = (const float4*)&red2[(t >> 2) * REDS];
            int k = t & 3;
            float s = 0.f;
            #pragma unroll
            for (int c4 = 0; c4 < 8; ++c4) {
                float4 x = rr[k + c4 * 4];
                s += (x.x + x.y) + (x.z + x.w);
            }
            s += __shfl_xor(s, 1);
            s += __shfl_xor(s, 2);
            if (k == 0)
                out[(size_t)bi * 512 + jt * 32 + (t >> 2)] = s + bo0;
        }
    }
}

// ---------------------------------------------------------------------------
extern "C" void kernel_launch(void* const* d_in, const int* in_sizes, int n_in,
                              void* d_out, int out_size, void* d_ws, size_t ws_size,
                              hipStream_t stream) {
    const float* Q   = (const float*)d_in[0];
    const float* K   = (const float*)d_in[1];
    const float* Wq  = (const float*)d_in[2];
    const float* Wk  = (const float*)d_in[3];
    const float* g   = (const float*)d_in[4];
    const float* bln = (const float*)d_in[5];
    const float* Wu  = (const float*)d_in[6];
    const float* bu  = (const float*)d_in[7];
    const float* Wv  = (const float*)d_in[8];
    const float* bv  = (const float*)d_in[9];
    const float* Wo  = (const float*)d_in[10];
    const float* bo  = (const float*)d_in[11];
    float* ws  = (float*)d_ws;
    float* out = (float*)d_out;

    hipLaunchKernelGGL(k_prep, dim3(24), dim3(256), 0, stream, Wu, bu, Wv, bv, g, bln, Wo, Wq, Wk, ws);
    hipLaunchKernelGGL(k_proj, dim3(256), dim3(256), 0, stream, Q, K, ws);
    hipLaunchKernelGGL(k_main, dim3(2048), dim3(512), 0, stream, ws, out, Wo, bo);
}